// Round 9
// baseline (439.301 us; speedup 1.0000x reference)
//
#include <hip/hip_runtime.h>

#define WAVE 64
#define BROWS 256        // rows per bucket (bucket = node >> 8)
#define NBKT_MAX 1024
#define CMAX 16          // max per-thread chunk in k_scanBkt (nJ <= 256*CMAX)
#define SRCMASK 0x3FFFF  // 18-bit src field in packed bins entry

// z layout is SLICE-MAJOR: z[slice][node][8 floats], slice in [0,8).
// Slice region = N*32 B (~4.8 MB) -> fits one XCD's L2. SPMM blocks pick
// slice = blockIdx&7 so (with round-robin dispatch) each XCD's gathers stay
// inside its own L2-resident slice.

// ---------------- phase 1: per-block bucket histogram, coalesced row write ------
__global__ void k_hist(const int* __restrict__ eu, const int* __restrict__ ei,
                       int nE, int nU, int nBkt, int nJg, int* __restrict__ cntBB) {
    __shared__ int h[NBKT_MAX];
    for (int i = threadIdx.x; i < nBkt; i += 256) h[i] = 0;
    __syncthreads();
    int e = blockIdx.x * 256 + threadIdx.x;
    if (e < nE) {
        atomicAdd(&h[eu[e] >> 8], 1);
        atomicAdd(&h[(nU + ei[e]) >> 8], 1);
    }
    __syncthreads();
    int j = (blockIdx.x & 7) * nJg + (blockIdx.x >> 3);   // XCD-affine block order
    int* dst = cntBB + (size_t)j * nBkt;
    for (int i = threadIdx.x; i < nBkt; i += 256) dst[i] = h[i];
}

// ---------------- phase 2a: per-bucket scan over blocks -> fragment bases --------
__global__ void k_scanBkt(const int* __restrict__ cntBB, int* __restrict__ baseBB,
                          int* __restrict__ bktTot, int nBkt, int nJ) {
    __shared__ int s[256];
    int b = blockIdx.x, t = threadIdx.x;
    int C = (nJ + 255) / 256;
    int vals[CMAX];
    int sum = 0;
    for (int k = 0; k < CMAX; k++) {
        if (k >= C) break;
        int j = t * C + k;
        int v = (j < nJ) ? cntBB[(size_t)j * nBkt + b] : 0;
        vals[k] = v; sum += v;
    }
    s[t] = sum;
    __syncthreads();
    for (int o = 1; o < 256; o <<= 1) {
        int x = (t >= o) ? s[t - o] : 0;
        __syncthreads();
        s[t] += x;
        __syncthreads();
    }
    int run = s[t] - sum;  // exclusive
    for (int k = 0; k < CMAX; k++) {
        if (k >= C) break;
        int j = t * C + k;
        if (j < nJ) { baseBB[(size_t)b * nJ + j] = run; run += vals[k]; }
    }
    if (t == 0) bktTot[b] = s[255];
}

// ---------------- phase 2b: scan bucket totals -> bktBase, row_ptr[N] ------------
__global__ void k_scanTot(const int* __restrict__ bktTot, int* __restrict__ bktBase,
                          int* __restrict__ row_ptr, int nBkt, int N, int total) {
    __shared__ int s[1024];
    int t = threadIdx.x;
    int v = (t < nBkt) ? bktTot[t] : 0;
    s[t] = v;
    __syncthreads();
    for (int o = 1; o < 1024; o <<= 1) {
        int x = (t >= o) ? s[t - o] : 0;
        __syncthreads();
        s[t] += x;
        __syncthreads();
    }
    if (t < nBkt) bktBase[t] = s[t] - v;
    if (t == 0) { bktBase[nBkt] = total; row_ptr[N] = total; }
}

// ---------------- phase 3: bin packed entries; LDS atomics only ------------------
// entry = ((dst & 255) << 18) | src   (src < 2^18)
__global__ void k_bin(const int* __restrict__ eu, const int* __restrict__ ei,
                      int nE, int nU, int nBkt, int nJ, int nJg,
                      const int* __restrict__ baseBB, const int* __restrict__ bktBase,
                      int* __restrict__ bins) {
    __shared__ int cur[NBKT_MAX];
    int j = (blockIdx.x & 7) * nJg + (blockIdx.x >> 3);
    for (int i = threadIdx.x; i < nBkt; i += 256)
        cur[i] = bktBase[i] + baseBB[(size_t)i * nJ + j];
    __syncthreads();
    int e = blockIdx.x * 256 + threadIdx.x;
    if (e >= nE) return;
    int u = eu[e];
    int v = nU + ei[e];
    int p1 = atomicAdd(&cur[u >> 8], 1);   // LDS atomic
    int p2 = atomicAdd(&cur[v >> 8], 1);
    __builtin_nontemporal_store(((u & 255) << 18) | v, &bins[p1]);
    __builtin_nontemporal_store(((v & 255) << 18) | u, &bins[p2]);
}

// ---------------- phase 4: per-bucket CSR finalize + fused slice-major z0 init ---
__global__ void k_csr(const int* __restrict__ bins, const int* __restrict__ bktBase,
                      int N, int nU,
                      const float* __restrict__ ue, const float* __restrict__ ie,
                      int* __restrict__ row_ptr, int* __restrict__ cnt,
                      int* __restrict__ col, float* __restrict__ z0) {
    __shared__ int h[BROWS], s[BROWS], cur[BROWS];
    __shared__ float sInv[BROWS];
    int b = blockIdx.x, t = threadIdx.x;
    int base = bktBase[b];
    int n = bktBase[b + 1] - base;
    h[t] = 0;
    __syncthreads();
    for (int i = t; i < n; i += BROWS)
        atomicAdd(&h[bins[base + i] >> 18], 1);
    __syncthreads();
    int v = h[t];
    s[t] = v;
    __syncthreads();
    for (int o = 1; o < BROWS; o <<= 1) {
        int x = (t >= o) ? s[t - o] : 0;
        __syncthreads();
        s[t] += x;
        __syncthreads();
    }
    int excl = s[t] - v;
    int row = b * BROWS + t;
    if (row < N) {
        row_ptr[row] = base + excl;
        cnt[row] = v;
    }
    sInv[t] = (v > 0) ? (1.0f / sqrtf((float)v)) : 0.0f;
    cur[t] = excl;
    __syncthreads();
    // fused z0 = inv .* x0, written slice-major
    int rf = t & 15;            // float4 index within row (0..15)
    int rg = t >> 4;            // row subgroup
    int slice = rf >> 1, hh = rf & 1;
    for (int pass = 0; pass < 16; pass++) {
        int r = pass * 16 + rg;
        int rr = b * BROWS + r;
        if (rr < N) {
            const float4* src = (rr < nU)
                ? ((const float4*)ue) + (size_t)rr * 16
                : ((const float4*)ie) + (size_t)(rr - nU) * 16;
            float4 val = src[rf];
            float sc = sInv[r];
            val.x *= sc; val.y *= sc; val.z *= sc; val.w *= sc;
            ((float4*)z0)[((size_t)slice * N + rr) * 2 + hh] = val;
        }
    }
    // placement
    for (int i = t; i < n; i += BROWS) {
        int p = bins[base + i];
        int pos = base + atomicAdd(&cur[p >> 18], 1);
        col[pos] = p & SRCMASK;
    }
}

// ---------------- SPMM (slice-per-XCD) + fused batch-accumulate tail -------------
// Main blocks: slice = blockIdx&7; 2-lane unit per row; 128 rows/block.
// Tail blocks at layer l accumulate x_l = sqrt(deg)*z_l from INPUT z (slice-major).
// mode==0 (layer 0): acc = x0 read directly from ue/ie (covers deg==0 nodes).
__global__ void k_spmm(const int* __restrict__ row_ptr, const int* __restrict__ col,
                       const float* __restrict__ x, float* __restrict__ y, int N,
                       int nBlkMain,
                       const int* __restrict__ users, const int* __restrict__ items,
                       int B, int nU, const int* __restrict__ cnt,
                       const float* __restrict__ ue, const float* __restrict__ ie,
                       float* __restrict__ acc, int mode) {
    int t = threadIdx.x;
    const float4* x4 = (const float4*)x;
    if ((int)blockIdx.x < nBlkMain) {
        int slice = blockIdx.x & 7;
        int row = (blockIdx.x >> 3) * 128 + (t >> 1);
        int hh = t & 1;
        if (row >= N) return;
        const float4* xs = x4 + (size_t)slice * N * 2;
        int s = row_ptr[row], e = row_ptr[row + 1];
        float4 a0 = make_float4(0.f, 0.f, 0.f, 0.f);
        float4 a1 = make_float4(0.f, 0.f, 0.f, 0.f);
        int j = s;
        for (; j + 1 < e; j += 2) {
            int c0 = col[j];
            int c1 = col[j + 1];
            float4 v0 = xs[(size_t)c0 * 2 + hh];
            float4 v1 = xs[(size_t)c1 * 2 + hh];
            a0.x += v0.x; a0.y += v0.y; a0.z += v0.z; a0.w += v0.w;
            a1.x += v1.x; a1.y += v1.y; a1.z += v1.z; a1.w += v1.w;
        }
        if (j < e) {
            int c = col[j];
            float4 v = xs[(size_t)c * 2 + hh];
            a0.x += v.x; a0.y += v.y; a0.z += v.z; a0.w += v.w;
        }
        float rdeg = (e > s) ? (1.0f / (float)(e - s)) : 0.0f;
        a0.x = (a0.x + a1.x) * rdeg;
        a0.y = (a0.y + a1.y) * rdeg;
        a0.z = (a0.z + a1.z) * rdeg;
        a0.w = (a0.w + a1.w) * rdeg;
        ((float4*)y)[((size_t)slice * N + row) * 2 + hh] = a0;
    } else {
        int grp = t >> 4, f4 = t & 15;
        int b = (blockIdx.x - nBlkMain) * 16 + grp;
        if (b >= 2 * B) return;
        float4 c;
        if (mode == 0) {
            const float4* x0 = (b < B)
                ? ((const float4*)ue) + (size_t)users[b] * 16
                : ((const float4*)ie) + (size_t)items[b - B] * 16;
            c = x0[f4];
        } else {
            int row = (b < B) ? users[b] : (nU + items[b - B]);
            float f = sqrtf((float)cnt[row]);
            float4 v = x4[((size_t)(f4 >> 1) * N + row) * 2 + (f4 & 1)];
            c = ((const float4*)acc)[(size_t)b * 16 + f4];
            c.x += f * v.x; c.y += f * v.y; c.z += f * v.z; c.w += f * v.w;
        }
        ((float4*)acc)[(size_t)b * 16 + f4] = c;
    }
}

// ---------------- final: add z4 term (slice-major), then gamma = dot/25 ----------
__global__ void k_dot(const float* __restrict__ acc, const float* __restrict__ z4,
                      const int* __restrict__ users, const int* __restrict__ items,
                      const int* __restrict__ cnt, int B, int nU, int N,
                      float* __restrict__ out) {
    int b = blockIdx.x * (blockDim.x >> 6) + (threadIdx.x >> 6);
    int lane = threadIdx.x & 63;
    if (b >= B) return;
    int urow = users[b];
    int irow = nU + items[b];
    float fu = sqrtf((float)cnt[urow]);
    float fi = sqrtf((float)cnt[irow]);
    int slice = lane >> 3, fi8 = lane & 7;
    float zu = z4[((size_t)slice * N + urow) * 8 + fi8];
    float zi = z4[((size_t)slice * N + irow) * 8 + fi8];
    float au = acc[(size_t)b * 64 + lane]       + fu * zu;
    float ai = acc[(size_t)(b + B) * 64 + lane] + fi * zi;
    float p = au * ai;
    #pragma unroll
    for (int o = 32; o > 0; o >>= 1) p += __shfl_down(p, o, WAVE);
    if (lane == 0) out[b] = p * (1.0f / 25.0f);
}

extern "C" void kernel_launch(void* const* d_in, const int* in_sizes, int n_in,
                              void* d_out, int out_size, void* d_ws, size_t ws_size,
                              hipStream_t stream) {
    const int*   users = (const int*)d_in[0];
    const int*   items = (const int*)d_in[1];
    const int*   eu    = (const int*)d_in[2];
    const int*   ei    = (const int*)d_in[3];
    const float* ue    = (const float*)d_in[4];
    const float* ie    = (const float*)d_in[5];
    float* out = (float*)d_out;

    const int D  = 64;
    const int B  = in_sizes[0];
    const int nE = in_sizes[2];
    const int nU = in_sizes[4] / D;
    const int nI = in_sizes[5] / D;
    const int N  = nU + nI;
    const int nBkt = (N + BROWS - 1) / BROWS;   // 586 (<= NBKT_MAX required)
    const int total = 2 * nE;

    const int nBlkE = (nE + 255) / 256;         // 2344
    const int nJg   = (nBlkE + 7) / 8;          // 293
    const int nJ    = 8 * nJg;                  // 2344 here (== nBlkE -> no memset)

    // ---- carve workspace (256B-aligned chunks) ----
    char* p = (char*)d_ws;
    auto alloc = [&](size_t bytes) -> void* {
        void* r = (void*)p;
        p += (bytes + 255) & ~(size_t)255;
        return r;
    };
    int*   cntBB   = (int*)  alloc((size_t)nJ * nBkt * 4);     // 5.5 MB
    int*   baseBB  = (int*)  alloc((size_t)nBkt * nJ * 4);     // 5.5 MB
    int*   bktTot  = (int*)  alloc((size_t)nBkt * 4);
    int*   bktBase = (int*)  alloc((size_t)(nBkt + 1) * 4);
    int*   bins    = (int*)  alloc((size_t)total * 4);         // 4.8 MB packed
    int*   col     = (int*)  alloc((size_t)total * 4);         // 4.8 MB
    int*   row_ptr = (int*)  alloc((size_t)(N + 1) * 4);
    int*   cnt     = (int*)  alloc((size_t)N * 4);
    float* za      = (float*)alloc((size_t)N * D * 4);         // slice-major
    float* zb      = (float*)alloc((size_t)N * D * 4);         // slice-major
    float* acc     = (float*)alloc((size_t)2 * B * D * 4);

    // ---- build CSR: zero global atomics, fused z0 init ----
    if (nJ != nBlkE)
        hipMemsetAsync(cntBB, 0, (size_t)nJ * nBkt * 4, stream);
    k_hist<<<nBlkE, 256, 0, stream>>>(eu, ei, nE, nU, nBkt, nJg, cntBB);
    k_scanBkt<<<nBkt, 256, 0, stream>>>(cntBB, baseBB, bktTot, nBkt, nJ);
    k_scanTot<<<1, 1024, 0, stream>>>(bktTot, bktBase, row_ptr, nBkt, N, total);
    k_bin<<<nBlkE, 256, 0, stream>>>(eu, ei, nE, nU, nBkt, nJ, nJg, baseBB, bktBase, bins);
    k_csr<<<nBkt, BROWS, 0, stream>>>(bins, bktBase, N, nU, ue, ie,
                                      row_ptr, cnt, col, za);

    // ---- 4 propagation layers in z-space, batch-accumulate fused into tail ------
    const int nBlkMain = ((N + 127) / 128) * 8;   // slice = blockIdx&7
    const int nBlkTail = (2 * B + 15) / 16;
    float* zin = za;
    float* zout = zb;
    for (int l = 0; l < 4; l++) {
        k_spmm<<<nBlkMain + nBlkTail, 256, 0, stream>>>(
            row_ptr, col, zin, zout, N, nBlkMain,
            users, items, B, nU, cnt, ue, ie, acc, (l == 0) ? 0 : 1);
        float* t = zin; zin = zout; zout = t;
    }

    // ---- final: z4 term + dot ----
    k_dot<<<(B + 3) / 4, 256, 0, stream>>>(acc, zin, users, items, cnt, B, nU, N, out);
}

// Round 10
// 377.690 us; speedup vs baseline: 1.1631x; 1.1631x over previous
//
#include <hip/hip_runtime.h>

#define WAVE 64
#define BROWS 256        // rows per bucket (bucket = node >> 8)
#define NBKT_MAX 1024
#define CMAX 16          // max per-thread chunk in k_scanBkt (nJ <= 256*CMAX)
#define SRCMASK 0x3FFFF  // 18-bit src field in packed bins entry

// z layout: SLICE-MAJOR at line granularity: z[slice][node][16 floats], 4 slices.
// Slice region = N*64 B (~9.6 MB) served by an XCD PAIR (blocks 2s,2s+1 of each
// 8-block group). Gather unit = 4 lanes x float4 = one full 64B line: no waste.

// ---------------- phase 1: per-block bucket histogram, coalesced row write ------
__global__ void k_hist(const int* __restrict__ eu, const int* __restrict__ ei,
                       int nE, int nU, int nBkt, int nJg, int* __restrict__ cntBB) {
    __shared__ int h[NBKT_MAX];
    for (int i = threadIdx.x; i < nBkt; i += 256) h[i] = 0;
    __syncthreads();
    int e = blockIdx.x * 256 + threadIdx.x;
    if (e < nE) {
        atomicAdd(&h[eu[e] >> 8], 1);
        atomicAdd(&h[(nU + ei[e]) >> 8], 1);
    }
    __syncthreads();
    int j = (blockIdx.x & 7) * nJg + (blockIdx.x >> 3);   // XCD-affine block order
    int* dst = cntBB + (size_t)j * nBkt;
    for (int i = threadIdx.x; i < nBkt; i += 256) dst[i] = h[i];
}

// ---------------- phase 2a: per-bucket scan over blocks -> fragment bases --------
__global__ void k_scanBkt(const int* __restrict__ cntBB, int* __restrict__ baseBB,
                          int* __restrict__ bktTot, int nBkt, int nJ) {
    __shared__ int s[256];
    int b = blockIdx.x, t = threadIdx.x;
    int C = (nJ + 255) / 256;
    int vals[CMAX];
    int sum = 0;
    for (int k = 0; k < CMAX; k++) {
        if (k >= C) break;
        int j = t * C + k;
        int v = (j < nJ) ? cntBB[(size_t)j * nBkt + b] : 0;
        vals[k] = v; sum += v;
    }
    s[t] = sum;
    __syncthreads();
    for (int o = 1; o < 256; o <<= 1) {
        int x = (t >= o) ? s[t - o] : 0;
        __syncthreads();
        s[t] += x;
        __syncthreads();
    }
    int run = s[t] - sum;  // exclusive
    for (int k = 0; k < CMAX; k++) {
        if (k >= C) break;
        int j = t * C + k;
        if (j < nJ) { baseBB[(size_t)b * nJ + j] = run; run += vals[k]; }
    }
    if (t == 0) bktTot[b] = s[255];
}

// ---------------- phase 2b: scan bucket totals -> bktBase, row_ptr[N] ------------
__global__ void k_scanTot(const int* __restrict__ bktTot, int* __restrict__ bktBase,
                          int* __restrict__ row_ptr, int nBkt, int N, int total) {
    __shared__ int s[1024];
    int t = threadIdx.x;
    int v = (t < nBkt) ? bktTot[t] : 0;
    s[t] = v;
    __syncthreads();
    for (int o = 1; o < 1024; o <<= 1) {
        int x = (t >= o) ? s[t - o] : 0;
        __syncthreads();
        s[t] += x;
        __syncthreads();
    }
    if (t < nBkt) bktBase[t] = s[t] - v;
    if (t == 0) { bktBase[nBkt] = total; row_ptr[N] = total; }
}

// ---------------- phase 3: bin packed entries; LDS atomics only ------------------
// entry = ((dst & 255) << 18) | src   (src < 2^18)
__global__ void k_bin(const int* __restrict__ eu, const int* __restrict__ ei,
                      int nE, int nU, int nBkt, int nJ, int nJg,
                      const int* __restrict__ baseBB, const int* __restrict__ bktBase,
                      int* __restrict__ bins) {
    __shared__ int cur[NBKT_MAX];
    int j = (blockIdx.x & 7) * nJg + (blockIdx.x >> 3);
    for (int i = threadIdx.x; i < nBkt; i += 256)
        cur[i] = bktBase[i] + baseBB[(size_t)i * nJ + j];
    __syncthreads();
    int e = blockIdx.x * 256 + threadIdx.x;
    if (e >= nE) return;
    int u = eu[e];
    int v = nU + ei[e];
    int p1 = atomicAdd(&cur[u >> 8], 1);   // LDS atomic
    int p2 = atomicAdd(&cur[v >> 8], 1);
    __builtin_nontemporal_store(((u & 255) << 18) | v, &bins[p1]);
    __builtin_nontemporal_store(((v & 255) << 18) | u, &bins[p2]);
}

// ---------------- phase 4: per-bucket CSR finalize + fused slice-major z0 init ---
__global__ void k_csr(const int* __restrict__ bins, const int* __restrict__ bktBase,
                      int N, int nU,
                      const float* __restrict__ ue, const float* __restrict__ ie,
                      int* __restrict__ row_ptr, int* __restrict__ cnt,
                      int* __restrict__ col, float* __restrict__ z0) {
    __shared__ int h[BROWS], s[BROWS], cur[BROWS];
    __shared__ float sInv[BROWS];
    int b = blockIdx.x, t = threadIdx.x;
    int base = bktBase[b];
    int n = bktBase[b + 1] - base;
    h[t] = 0;
    __syncthreads();
    for (int i = t; i < n; i += BROWS)
        atomicAdd(&h[bins[base + i] >> 18], 1);
    __syncthreads();
    int v = h[t];
    s[t] = v;
    __syncthreads();
    for (int o = 1; o < BROWS; o <<= 1) {
        int x = (t >= o) ? s[t - o] : 0;
        __syncthreads();
        s[t] += x;
        __syncthreads();
    }
    int excl = s[t] - v;
    int row = b * BROWS + t;
    if (row < N) {
        row_ptr[row] = base + excl;
        cnt[row] = v;
    }
    sInv[t] = (v > 0) ? (1.0f / sqrtf((float)v)) : 0.0f;
    cur[t] = excl;
    __syncthreads();
    // fused z0 = inv .* x0, written slice-major: z[slice][node][4 x float4]
    int rf = t & 15;            // float4 index within row (0..15)
    int rg = t >> 4;            // row subgroup
    int slice = rf >> 2, q = rf & 3;
    for (int pass = 0; pass < 16; pass++) {
        int r = pass * 16 + rg;
        int rr = b * BROWS + r;
        if (rr < N) {
            const float4* src = (rr < nU)
                ? ((const float4*)ue) + (size_t)rr * 16
                : ((const float4*)ie) + (size_t)(rr - nU) * 16;
            float4 val = src[rf];
            float sc = sInv[r];
            val.x *= sc; val.y *= sc; val.z *= sc; val.w *= sc;
            ((float4*)z0)[((size_t)slice * N + rr) * 4 + q] = val;
        }
    }
    // placement
    for (int i = t; i < n; i += BROWS) {
        int p = bins[base + i];
        int pos = base + atomicAdd(&cur[p >> 18], 1);
        col[pos] = p & SRCMASK;
    }
}

// ---------------- SPMM (line-granular slice per XCD-pair) + fused tail -----------
// Main blocks: low3=blockIdx&7; slice=low3>>1 (0..3); half=low3&1;
// 8 consecutive blocks cover 128 rows x 4 slices. Unit = 4 lanes x float4 = 64B.
__global__ void k_spmm(const int* __restrict__ row_ptr, const int* __restrict__ col,
                       const float* __restrict__ x, float* __restrict__ y, int N,
                       int nBlkMain,
                       const int* __restrict__ users, const int* __restrict__ items,
                       int B, int nU, const int* __restrict__ cnt,
                       const float* __restrict__ ue, const float* __restrict__ ie,
                       float* __restrict__ acc, int mode) {
    int t = threadIdx.x;
    const float4* x4 = (const float4*)x;
    if ((int)blockIdx.x < nBlkMain) {
        int low3 = blockIdx.x & 7;
        int slice = low3 >> 1;
        int half = low3 & 1;
        int unit = t >> 2;          // 0..63
        int q = t & 3;              // float4 within the 64B slice chunk
        int row = (blockIdx.x >> 3) * 128 + half * 64 + unit;
        if (row >= N) return;
        const float4* xs = x4 + (size_t)slice * N * 4;
        int s = row_ptr[row], e = row_ptr[row + 1];
        float4 a0 = make_float4(0.f, 0.f, 0.f, 0.f);
        float4 a1 = make_float4(0.f, 0.f, 0.f, 0.f);
        int j = s;
        for (; j + 1 < e; j += 2) {
            int c0 = col[j];
            int c1 = col[j + 1];
            float4 v0 = xs[(size_t)c0 * 4 + q];
            float4 v1 = xs[(size_t)c1 * 4 + q];
            a0.x += v0.x; a0.y += v0.y; a0.z += v0.z; a0.w += v0.w;
            a1.x += v1.x; a1.y += v1.y; a1.z += v1.z; a1.w += v1.w;
        }
        if (j < e) {
            int c = col[j];
            float4 v = xs[(size_t)c * 4 + q];
            a0.x += v.x; a0.y += v.y; a0.z += v.z; a0.w += v.w;
        }
        float rdeg = (e > s) ? (1.0f / (float)(e - s)) : 0.0f;
        a0.x = (a0.x + a1.x) * rdeg;
        a0.y = (a0.y + a1.y) * rdeg;
        a0.z = (a0.z + a1.z) * rdeg;
        a0.w = (a0.w + a1.w) * rdeg;
        ((float4*)y)[((size_t)slice * N + row) * 4 + q] = a0;
    } else {
        int grp = t >> 4, f4 = t & 15;
        int b = (blockIdx.x - nBlkMain) * 16 + grp;
        if (b >= 2 * B) return;
        float4 c;
        if (mode == 0) {
            const float4* x0 = (b < B)
                ? ((const float4*)ue) + (size_t)users[b] * 16
                : ((const float4*)ie) + (size_t)items[b - B] * 16;
            c = x0[f4];
        } else {
            int row = (b < B) ? users[b] : (nU + items[b - B]);
            float f = sqrtf((float)cnt[row]);
            float4 v = x4[((size_t)(f4 >> 2) * N + row) * 4 + (f4 & 3)];
            c = ((const float4*)acc)[(size_t)b * 16 + f4];
            c.x += f * v.x; c.y += f * v.y; c.z += f * v.z; c.w += f * v.w;
        }
        ((float4*)acc)[(size_t)b * 16 + f4] = c;
    }
}

// ---------------- final: add z4 term (slice-major), then gamma = dot/25 ----------
__global__ void k_dot(const float* __restrict__ acc, const float* __restrict__ z4,
                      const int* __restrict__ users, const int* __restrict__ items,
                      const int* __restrict__ cnt, int B, int nU, int N,
                      float* __restrict__ out) {
    int b = blockIdx.x * (blockDim.x >> 6) + (threadIdx.x >> 6);
    int lane = threadIdx.x & 63;
    if (b >= B) return;
    int urow = users[b];
    int irow = nU + items[b];
    float fu = sqrtf((float)cnt[urow]);
    float fi = sqrtf((float)cnt[irow]);
    int slice = lane >> 4, idx = lane & 15;
    float zu = z4[((size_t)slice * N + urow) * 16 + idx];
    float zi = z4[((size_t)slice * N + irow) * 16 + idx];
    float au = acc[(size_t)b * 64 + lane]       + fu * zu;
    float ai = acc[(size_t)(b + B) * 64 + lane] + fi * zi;
    float p = au * ai;
    #pragma unroll
    for (int o = 32; o > 0; o >>= 1) p += __shfl_down(p, o, WAVE);
    if (lane == 0) out[b] = p * (1.0f / 25.0f);
}

extern "C" void kernel_launch(void* const* d_in, const int* in_sizes, int n_in,
                              void* d_out, int out_size, void* d_ws, size_t ws_size,
                              hipStream_t stream) {
    const int*   users = (const int*)d_in[0];
    const int*   items = (const int*)d_in[1];
    const int*   eu    = (const int*)d_in[2];
    const int*   ei    = (const int*)d_in[3];
    const float* ue    = (const float*)d_in[4];
    const float* ie    = (const float*)d_in[5];
    float* out = (float*)d_out;

    const int D  = 64;
    const int B  = in_sizes[0];
    const int nE = in_sizes[2];
    const int nU = in_sizes[4] / D;
    const int nI = in_sizes[5] / D;
    const int N  = nU + nI;
    const int nBkt = (N + BROWS - 1) / BROWS;   // 586 (<= NBKT_MAX required)
    const int total = 2 * nE;

    const int nBlkE = (nE + 255) / 256;         // 2344
    const int nJg   = (nBlkE + 7) / 8;          // 293
    const int nJ    = 8 * nJg;                  // 2344 here (== nBlkE -> no memset)

    // ---- carve workspace (256B-aligned chunks) ----
    char* p = (char*)d_ws;
    auto alloc = [&](size_t bytes) -> void* {
        void* r = (void*)p;
        p += (bytes + 255) & ~(size_t)255;
        return r;
    };
    int*   cntBB   = (int*)  alloc((size_t)nJ * nBkt * 4);     // 5.5 MB
    int*   baseBB  = (int*)  alloc((size_t)nBkt * nJ * 4);     // 5.5 MB
    int*   bktTot  = (int*)  alloc((size_t)nBkt * 4);
    int*   bktBase = (int*)  alloc((size_t)(nBkt + 1) * 4);
    int*   bins    = (int*)  alloc((size_t)total * 4);         // 4.8 MB packed
    int*   col     = (int*)  alloc((size_t)total * 4);         // 4.8 MB
    int*   row_ptr = (int*)  alloc((size_t)(N + 1) * 4);
    int*   cnt     = (int*)  alloc((size_t)N * 4);
    float* za      = (float*)alloc((size_t)N * D * 4);         // slice-major (4x64B)
    float* zb      = (float*)alloc((size_t)N * D * 4);         // slice-major (4x64B)
    float* acc     = (float*)alloc((size_t)2 * B * D * 4);

    // ---- build CSR: zero global atomics, fused z0 init ----
    if (nJ != nBlkE)
        hipMemsetAsync(cntBB, 0, (size_t)nJ * nBkt * 4, stream);
    k_hist<<<nBlkE, 256, 0, stream>>>(eu, ei, nE, nU, nBkt, nJg, cntBB);
    k_scanBkt<<<nBkt, 256, 0, stream>>>(cntBB, baseBB, bktTot, nBkt, nJ);
    k_scanTot<<<1, 1024, 0, stream>>>(bktTot, bktBase, row_ptr, nBkt, N, total);
    k_bin<<<nBlkE, 256, 0, stream>>>(eu, ei, nE, nU, nBkt, nJ, nJg, baseBB, bktBase, bins);
    k_csr<<<nBkt, BROWS, 0, stream>>>(bins, bktBase, N, nU, ue, ie,
                                      row_ptr, cnt, col, za);

    // ---- 4 propagation layers in z-space, batch-accumulate fused into tail ------
    const int nBlkMain = ((N + 127) / 128) * 8;   // 128 rows x 4 slices per 8 blocks
    const int nBlkTail = (2 * B + 15) / 16;
    float* zin = za;
    float* zout = zb;
    for (int l = 0; l < 4; l++) {
        k_spmm<<<nBlkMain + nBlkTail, 256, 0, stream>>>(
            row_ptr, col, zin, zout, N, nBlkMain,
            users, items, B, nU, cnt, ue, ie, acc, (l == 0) ? 0 : 1);
        float* t = zin; zin = zout; zout = t;
    }

    // ---- final: z4 term + dot ----
    k_dot<<<(B + 3) / 4, 256, 0, stream>>>(acc, zin, users, items, cnt, B, nU, N, out);
}

// Round 11
// 299.566 us; speedup vs baseline: 1.4665x; 1.2608x over previous
//
#include <hip/hip_runtime.h>

#define WAVE 64
#define BROWS 256        // rows per bucket (bucket = node >> 8)
#define NBKT_MAX 1024
#define CMAX 16          // max per-thread chunk in k_scanBkt (nJ <= 256*CMAX)
#define SRCMASK 0x3FFFF  // 18-bit src field in packed bins entry

// z is stored BF16 row-major: z[node][64] (128 B/row). Gathers are demand-BW
// bound (R8 hit the 6.4 TB/s delivered ceiling in fp32); halving bytes is the
// only remaining lever. All accumulation stays fp32; only z rounds (RTNE).

__device__ __forceinline__ float bf2f(unsigned short v) {
    return __uint_as_float((unsigned)v << 16);
}
__device__ __forceinline__ unsigned short f2bf(float f) {
    unsigned u = __float_as_uint(f);
    u += 0x7FFF + ((u >> 16) & 1);   // round-to-nearest-even
    return (unsigned short)(u >> 16);
}

// ---------------- phase 1: per-block bucket histogram, coalesced row write ------
__global__ void k_hist(const int* __restrict__ eu, const int* __restrict__ ei,
                       int nE, int nU, int nBkt, int nJg, int* __restrict__ cntBB) {
    __shared__ int h[NBKT_MAX];
    for (int i = threadIdx.x; i < nBkt; i += 256) h[i] = 0;
    __syncthreads();
    int e = blockIdx.x * 256 + threadIdx.x;
    if (e < nE) {
        atomicAdd(&h[eu[e] >> 8], 1);
        atomicAdd(&h[(nU + ei[e]) >> 8], 1);
    }
    __syncthreads();
    int j = (blockIdx.x & 7) * nJg + (blockIdx.x >> 3);   // XCD-affine block order
    int* dst = cntBB + (size_t)j * nBkt;
    for (int i = threadIdx.x; i < nBkt; i += 256) dst[i] = h[i];
}

// ---------------- phase 2a: per-bucket scan over blocks -> fragment bases --------
__global__ void k_scanBkt(const int* __restrict__ cntBB, int* __restrict__ baseBB,
                          int* __restrict__ bktTot, int nBkt, int nJ) {
    __shared__ int s[256];
    int b = blockIdx.x, t = threadIdx.x;
    int C = (nJ + 255) / 256;
    int vals[CMAX];
    int sum = 0;
    for (int k = 0; k < CMAX; k++) {
        if (k >= C) break;
        int j = t * C + k;
        int v = (j < nJ) ? cntBB[(size_t)j * nBkt + b] : 0;
        vals[k] = v; sum += v;
    }
    s[t] = sum;
    __syncthreads();
    for (int o = 1; o < 256; o <<= 1) {
        int x = (t >= o) ? s[t - o] : 0;
        __syncthreads();
        s[t] += x;
        __syncthreads();
    }
    int run = s[t] - sum;  // exclusive
    for (int k = 0; k < CMAX; k++) {
        if (k >= C) break;
        int j = t * C + k;
        if (j < nJ) { baseBB[(size_t)b * nJ + j] = run; run += vals[k]; }
    }
    if (t == 0) bktTot[b] = s[255];
}

// ---------------- phase 2b: scan bucket totals -> bktBase, row_ptr[N] ------------
__global__ void k_scanTot(const int* __restrict__ bktTot, int* __restrict__ bktBase,
                          int* __restrict__ row_ptr, int nBkt, int N, int total) {
    __shared__ int s[1024];
    int t = threadIdx.x;
    int v = (t < nBkt) ? bktTot[t] : 0;
    s[t] = v;
    __syncthreads();
    for (int o = 1; o < 1024; o <<= 1) {
        int x = (t >= o) ? s[t - o] : 0;
        __syncthreads();
        s[t] += x;
        __syncthreads();
    }
    if (t < nBkt) bktBase[t] = s[t] - v;
    if (t == 0) { bktBase[nBkt] = total; row_ptr[N] = total; }
}

// ---------------- phase 3: bin packed entries; LDS atomics only ------------------
// entry = ((dst & 255) << 18) | src   (src < 2^18)
__global__ void k_bin(const int* __restrict__ eu, const int* __restrict__ ei,
                      int nE, int nU, int nBkt, int nJ, int nJg,
                      const int* __restrict__ baseBB, const int* __restrict__ bktBase,
                      int* __restrict__ bins) {
    __shared__ int cur[NBKT_MAX];
    int j = (blockIdx.x & 7) * nJg + (blockIdx.x >> 3);
    for (int i = threadIdx.x; i < nBkt; i += 256)
        cur[i] = bktBase[i] + baseBB[(size_t)i * nJ + j];
    __syncthreads();
    int e = blockIdx.x * 256 + threadIdx.x;
    if (e >= nE) return;
    int u = eu[e];
    int v = nU + ei[e];
    int p1 = atomicAdd(&cur[u >> 8], 1);   // LDS atomic
    int p2 = atomicAdd(&cur[v >> 8], 1);
    __builtin_nontemporal_store(((u & 255) << 18) | v, &bins[p1]);
    __builtin_nontemporal_store(((v & 255) << 18) | u, &bins[p2]);
}

// ---------------- phase 4: per-bucket CSR finalize + fused bf16 z0 init ----------
__global__ void k_csr(const int* __restrict__ bins, const int* __restrict__ bktBase,
                      int N, int nU,
                      const float* __restrict__ ue, const float* __restrict__ ie,
                      int* __restrict__ row_ptr, int* __restrict__ cnt,
                      int* __restrict__ col, unsigned short* __restrict__ z0) {
    __shared__ int h[BROWS], s[BROWS], cur[BROWS];
    __shared__ float sInv[BROWS];
    int b = blockIdx.x, t = threadIdx.x;
    int base = bktBase[b];
    int n = bktBase[b + 1] - base;
    h[t] = 0;
    __syncthreads();
    for (int i = t; i < n; i += BROWS)
        atomicAdd(&h[bins[base + i] >> 18], 1);
    __syncthreads();
    int v = h[t];
    s[t] = v;
    __syncthreads();
    for (int o = 1; o < BROWS; o <<= 1) {
        int x = (t >= o) ? s[t - o] : 0;
        __syncthreads();
        s[t] += x;
        __syncthreads();
    }
    int excl = s[t] - v;
    int row = b * BROWS + t;
    if (row < N) {
        row_ptr[row] = base + excl;
        cnt[row] = v;
    }
    sInv[t] = (v > 0) ? (1.0f / sqrtf((float)v)) : 0.0f;
    cur[t] = excl;
    __syncthreads();
    // fused z0 = inv .* x0 (bf16 RTNE), 16 rows per pass, coalesced
    int rf = t & 15;            // 4-dim chunk index within row (0..15)
    int rg = t >> 4;            // row subgroup
    for (int pass = 0; pass < 16; pass++) {
        int r = pass * 16 + rg;
        int rr = b * BROWS + r;
        if (rr < N) {
            const float4* src = (rr < nU)
                ? ((const float4*)ue) + (size_t)rr * 16
                : ((const float4*)ie) + (size_t)(rr - nU) * 16;
            float4 val = src[rf];
            float sc = sInv[r];
            ushort4 o;
            o.x = f2bf(val.x * sc);
            o.y = f2bf(val.y * sc);
            o.z = f2bf(val.z * sc);
            o.w = f2bf(val.w * sc);
            ((ushort4*)z0)[(size_t)rr * 16 + rf] = o;
        }
    }
    // placement
    for (int i = t; i < n; i += BROWS) {
        int p = bins[base + i];
        int pos = base + atomicAdd(&cur[p >> 18], 1);
        col[pos] = p & SRCMASK;
    }
}

// ---------------- SPMM (bf16 z, row-major) + fused batch-accumulate tail ---------
// Main blocks: 16-lane group per row (4 rows/wave), 8 B/lane gathers.
__global__ void k_spmm(const int* __restrict__ row_ptr, const int* __restrict__ col,
                       const unsigned short* __restrict__ x,
                       unsigned short* __restrict__ y, int N, int nBlkMain,
                       const int* __restrict__ users, const int* __restrict__ items,
                       int B, int nU, const int* __restrict__ cnt,
                       const float* __restrict__ ue, const float* __restrict__ ie,
                       float* __restrict__ acc, int mode) {
    int t = threadIdx.x;
    int grp = t >> 4, f4 = t & 15;
    const ushort4* x4 = (const ushort4*)x;
    if ((int)blockIdx.x < nBlkMain) {
        int row = blockIdx.x * 16 + grp;
        if (row >= N) return;
        int s = row_ptr[row], e = row_ptr[row + 1];
        float4 a0 = make_float4(0.f, 0.f, 0.f, 0.f);
        float4 a1 = make_float4(0.f, 0.f, 0.f, 0.f);
        int j = s;
        for (; j + 1 < e; j += 2) {
            int c0 = col[j];
            int c1 = col[j + 1];
            ushort4 v0 = x4[(size_t)c0 * 16 + f4];
            ushort4 v1 = x4[(size_t)c1 * 16 + f4];
            a0.x += bf2f(v0.x); a0.y += bf2f(v0.y);
            a0.z += bf2f(v0.z); a0.w += bf2f(v0.w);
            a1.x += bf2f(v1.x); a1.y += bf2f(v1.y);
            a1.z += bf2f(v1.z); a1.w += bf2f(v1.w);
        }
        if (j < e) {
            int c = col[j];
            ushort4 v = x4[(size_t)c * 16 + f4];
            a0.x += bf2f(v.x); a0.y += bf2f(v.y);
            a0.z += bf2f(v.z); a0.w += bf2f(v.w);
        }
        float rdeg = (e > s) ? (1.0f / (float)(e - s)) : 0.0f;
        ushort4 o;
        o.x = f2bf((a0.x + a1.x) * rdeg);
        o.y = f2bf((a0.y + a1.y) * rdeg);
        o.z = f2bf((a0.z + a1.z) * rdeg);
        o.w = f2bf((a0.w + a1.w) * rdeg);
        ((ushort4*)y)[(size_t)row * 16 + f4] = o;
    } else {
        int b = (blockIdx.x - nBlkMain) * 16 + grp;
        if (b >= 2 * B) return;
        float4 c;
        if (mode == 0) {
            // acc = x0 directly (exact fp32; covers deg==0 nodes)
            const float4* x0 = (b < B)
                ? ((const float4*)ue) + (size_t)users[b] * 16
                : ((const float4*)ie) + (size_t)items[b - B] * 16;
            c = x0[f4];
        } else {
            int row = (b < B) ? users[b] : (nU + items[b - B]);
            float f = sqrtf((float)cnt[row]);
            ushort4 v = x4[(size_t)row * 16 + f4];
            c = ((const float4*)acc)[(size_t)b * 16 + f4];
            c.x += f * bf2f(v.x); c.y += f * bf2f(v.y);
            c.z += f * bf2f(v.z); c.w += f * bf2f(v.w);
        }
        ((float4*)acc)[(size_t)b * 16 + f4] = c;
    }
}

// ---------------- final: add z4 term (bf16), then gamma = dot/25 -----------------
__global__ void k_dot(const float* __restrict__ acc, const unsigned short* __restrict__ z4,
                      const int* __restrict__ users, const int* __restrict__ items,
                      const int* __restrict__ cnt, int B, int nU,
                      float* __restrict__ out) {
    int b = blockIdx.x * (blockDim.x >> 6) + (threadIdx.x >> 6);
    int lane = threadIdx.x & 63;
    if (b >= B) return;
    int urow = users[b];
    int irow = nU + items[b];
    float fu = sqrtf((float)cnt[urow]);
    float fi = sqrtf((float)cnt[irow]);
    float zu = bf2f(z4[(size_t)urow * 64 + lane]);
    float zi = bf2f(z4[(size_t)irow * 64 + lane]);
    float au = acc[(size_t)b * 64 + lane]       + fu * zu;
    float ai = acc[(size_t)(b + B) * 64 + lane] + fi * zi;
    float p = au * ai;
    #pragma unroll
    for (int o = 32; o > 0; o >>= 1) p += __shfl_down(p, o, WAVE);
    if (lane == 0) out[b] = p * (1.0f / 25.0f);
}

extern "C" void kernel_launch(void* const* d_in, const int* in_sizes, int n_in,
                              void* d_out, int out_size, void* d_ws, size_t ws_size,
                              hipStream_t stream) {
    const int*   users = (const int*)d_in[0];
    const int*   items = (const int*)d_in[1];
    const int*   eu    = (const int*)d_in[2];
    const int*   ei    = (const int*)d_in[3];
    const float* ue    = (const float*)d_in[4];
    const float* ie    = (const float*)d_in[5];
    float* out = (float*)d_out;

    const int D  = 64;
    const int B  = in_sizes[0];
    const int nE = in_sizes[2];
    const int nU = in_sizes[4] / D;
    const int nI = in_sizes[5] / D;
    const int N  = nU + nI;
    const int nBkt = (N + BROWS - 1) / BROWS;   // 586 (<= NBKT_MAX required)
    const int total = 2 * nE;

    const int nBlkE = (nE + 255) / 256;         // 2344
    const int nJg   = (nBlkE + 7) / 8;          // 293
    const int nJ    = 8 * nJg;                  // 2344 here (== nBlkE -> no memset)

    // ---- carve workspace (256B-aligned chunks) ----
    char* p = (char*)d_ws;
    auto alloc = [&](size_t bytes) -> void* {
        void* r = (void*)p;
        p += (bytes + 255) & ~(size_t)255;
        return r;
    };
    int*   cntBB   = (int*)  alloc((size_t)nJ * nBkt * 4);     // 5.5 MB
    int*   baseBB  = (int*)  alloc((size_t)nBkt * nJ * 4);     // 5.5 MB
    int*   bktTot  = (int*)  alloc((size_t)nBkt * 4);
    int*   bktBase = (int*)  alloc((size_t)(nBkt + 1) * 4);
    int*   bins    = (int*)  alloc((size_t)total * 4);         // 4.8 MB packed
    int*   col     = (int*)  alloc((size_t)total * 4);         // 4.8 MB
    int*   row_ptr = (int*)  alloc((size_t)(N + 1) * 4);
    int*   cnt     = (int*)  alloc((size_t)N * 4);
    unsigned short* za = (unsigned short*)alloc((size_t)N * D * 2);  // 19.2 MB bf16
    unsigned short* zb = (unsigned short*)alloc((size_t)N * D * 2);  // 19.2 MB bf16
    float* acc     = (float*)alloc((size_t)2 * B * D * 4);

    // ---- build CSR: zero global atomics, fused z0 init ----
    if (nJ != nBlkE)
        hipMemsetAsync(cntBB, 0, (size_t)nJ * nBkt * 4, stream);
    k_hist<<<nBlkE, 256, 0, stream>>>(eu, ei, nE, nU, nBkt, nJg, cntBB);
    k_scanBkt<<<nBkt, 256, 0, stream>>>(cntBB, baseBB, bktTot, nBkt, nJ);
    k_scanTot<<<1, 1024, 0, stream>>>(bktTot, bktBase, row_ptr, nBkt, N, total);
    k_bin<<<nBlkE, 256, 0, stream>>>(eu, ei, nE, nU, nBkt, nJ, nJg, baseBB, bktBase, bins);
    k_csr<<<nBkt, BROWS, 0, stream>>>(bins, bktBase, N, nU, ue, ie,
                                      row_ptr, cnt, col, za);

    // ---- 4 propagation layers in z-space, batch-accumulate fused into tail ------
    const int nBlkMain = (N + 15) / 16;
    const int nBlkTail = (2 * B + 15) / 16;
    unsigned short* zin = za;
    unsigned short* zout = zb;
    for (int l = 0; l < 4; l++) {
        k_spmm<<<nBlkMain + nBlkTail, 256, 0, stream>>>(
            row_ptr, col, zin, zout, N, nBlkMain,
            users, items, B, nU, cnt, ue, ie, acc, (l == 0) ? 0 : 1);
        unsigned short* t = zin; zin = zout; zout = t;
    }

    // ---- final: z4 term + dot ----
    k_dot<<<(B + 3) / 4, 256, 0, stream>>>(acc, zin, users, items, cnt, B, nU, out);
}

// Round 12
// 267.649 us; speedup vs baseline: 1.6413x; 1.1192x over previous
//
#include <hip/hip_runtime.h>

#define WAVE 64
#define BROWS 256        // rows per bucket (bucket = node >> 8)
#define NBKT_MAX 1024
#define CMAX 4           // max per-thread chunk in k_scanBkt (nJ <= 256*CMAX)
#define SRCMASK 0x3FFFF  // 18-bit src field in packed bins entry
#define EPB 2048         // edges per build block (256 threads x 8)

// z stored BF16 row-major z[node][64] (128 B). Accumulation fp32 throughout.

__device__ __forceinline__ float bf2f(unsigned short v) {
    return __uint_as_float((unsigned)v << 16);
}
__device__ __forceinline__ unsigned short f2bf(float f) {
    unsigned u = __float_as_uint(f);
    u += 0x7FFF + ((u >> 16) & 1);   // round-to-nearest-even
    return (unsigned short)(u >> 16);
}

// ---------------- phase 1: per-block bucket histogram (2048 edges/block) --------
__global__ void k_hist(const int* __restrict__ eu, const int* __restrict__ ei,
                       int nE, int nU, int nBkt, int nJg, int* __restrict__ cntBB) {
    __shared__ int h4[4 * NBKT_MAX];
    for (int i = threadIdx.x; i < 4 * nBkt; i += 256) h4[i] = 0;
    __syncthreads();
    int* hw = h4 + (threadIdx.x >> 6) * nBkt;    // per-wave sub-histogram
    const int4* eu4 = (const int4*)eu;
    const int4* ei4 = (const int4*)ei;
    for (int pass = 0; pass < 2; pass++) {
        int i4 = blockIdx.x * 512 + pass * 256 + threadIdx.x;
        int e0 = i4 * 4;
        if (e0 + 3 < nE) {
            int4 u = eu4[i4];
            int4 v = ei4[i4];
            atomicAdd(&hw[u.x >> 8], 1); atomicAdd(&hw[(nU + v.x) >> 8], 1);
            atomicAdd(&hw[u.y >> 8], 1); atomicAdd(&hw[(nU + v.y) >> 8], 1);
            atomicAdd(&hw[u.z >> 8], 1); atomicAdd(&hw[(nU + v.z) >> 8], 1);
            atomicAdd(&hw[u.w >> 8], 1); atomicAdd(&hw[(nU + v.w) >> 8], 1);
        } else if (e0 < nE) {
            for (int e = e0; e < nE; e++) {
                atomicAdd(&hw[eu[e] >> 8], 1);
                atomicAdd(&hw[(nU + ei[e]) >> 8], 1);
            }
        }
    }
    __syncthreads();
    int j = (blockIdx.x & 7) * nJg + (blockIdx.x >> 3);   // XCD-affine block order
    int* dst = cntBB + (size_t)j * nBkt;
    for (int i = threadIdx.x; i < nBkt; i += 256)
        dst[i] = h4[i] + h4[nBkt + i] + h4[2 * nBkt + i] + h4[3 * nBkt + i];
}

// ---------------- phase 2a: per-bucket scan over blocks -> fragment bases --------
__global__ void k_scanBkt(const int* __restrict__ cntBB, int* __restrict__ baseBB,
                          int* __restrict__ bktTot, int nBkt, int nJ) {
    __shared__ int s[256];
    int b = blockIdx.x, t = threadIdx.x;
    int C = (nJ + 255) / 256;
    int vals[CMAX];
    int sum = 0;
    for (int k = 0; k < CMAX; k++) {
        if (k >= C) break;
        int j = t * C + k;
        int v = (j < nJ) ? cntBB[(size_t)j * nBkt + b] : 0;
        vals[k] = v; sum += v;
    }
    s[t] = sum;
    __syncthreads();
    for (int o = 1; o < 256; o <<= 1) {
        int x = (t >= o) ? s[t - o] : 0;
        __syncthreads();
        s[t] += x;
        __syncthreads();
    }
    int run = s[t] - sum;  // exclusive
    for (int k = 0; k < CMAX; k++) {
        if (k >= C) break;
        int j = t * C + k;
        if (j < nJ) { baseBB[(size_t)b * nJ + j] = run; run += vals[k]; }
    }
    if (t == 0) bktTot[b] = s[255];
}

// ---------------- phase 2b: scan bucket totals -> bktBase, row_ptr[N] ------------
__global__ void k_scanTot(const int* __restrict__ bktTot, int* __restrict__ bktBase,
                          int* __restrict__ row_ptr, int nBkt, int N, int total) {
    __shared__ int s[1024];
    int t = threadIdx.x;
    int v = (t < nBkt) ? bktTot[t] : 0;
    s[t] = v;
    __syncthreads();
    for (int o = 1; o < 1024; o <<= 1) {
        int x = (t >= o) ? s[t - o] : 0;
        __syncthreads();
        s[t] += x;
        __syncthreads();
    }
    if (t < nBkt) bktBase[t] = s[t] - v;
    if (t == 0) { bktBase[nBkt] = total; row_ptr[N] = total; }
}

// ---------------- phase 3: bin packed entries (2048 edges/block) -----------------
// entry = ((dst & 255) << 18) | src
__global__ void k_bin(const int* __restrict__ eu, const int* __restrict__ ei,
                      int nE, int nU, int nBkt, int nJ, int nJg,
                      const int* __restrict__ baseBB, const int* __restrict__ bktBase,
                      int* __restrict__ bins) {
    __shared__ int cur[NBKT_MAX];
    int j = (blockIdx.x & 7) * nJg + (blockIdx.x >> 3);
    for (int i = threadIdx.x; i < nBkt; i += 256)
        cur[i] = bktBase[i] + baseBB[(size_t)i * nJ + j];
    __syncthreads();
    const int4* eu4 = (const int4*)eu;
    const int4* ei4 = (const int4*)ei;
    for (int pass = 0; pass < 2; pass++) {
        int i4 = blockIdx.x * 512 + pass * 256 + threadIdx.x;
        int e0 = i4 * 4;
        if (e0 + 3 < nE) {
            int4 uu = eu4[i4];
            int4 vv = ei4[i4];
            #pragma unroll
            for (int k = 0; k < 4; k++) {
                int u = (k == 0) ? uu.x : (k == 1) ? uu.y : (k == 2) ? uu.z : uu.w;
                int i2 = (k == 0) ? vv.x : (k == 1) ? vv.y : (k == 2) ? vv.z : vv.w;
                int v = nU + i2;
                int p1 = atomicAdd(&cur[u >> 8], 1);
                int p2 = atomicAdd(&cur[v >> 8], 1);
                __builtin_nontemporal_store(((u & 255) << 18) | v, &bins[p1]);
                __builtin_nontemporal_store(((v & 255) << 18) | u, &bins[p2]);
            }
        } else if (e0 < nE) {
            for (int e = e0; e < nE; e++) {
                int u = eu[e];
                int v = nU + ei[e];
                int p1 = atomicAdd(&cur[u >> 8], 1);
                int p2 = atomicAdd(&cur[v >> 8], 1);
                __builtin_nontemporal_store(((u & 255) << 18) | v, &bins[p1]);
                __builtin_nontemporal_store(((v & 255) << 18) | u, &bins[p2]);
            }
        }
    }
}

// ---------------- phase 4: CSR finalize, per-wave hist/cursors, fused z0 ---------
__global__ void k_csrz(const int* __restrict__ bins, const int* __restrict__ bktBase,
                       int N, int nU,
                       const float* __restrict__ ue, const float* __restrict__ ie,
                       int* __restrict__ row_ptr, int* __restrict__ col,
                       unsigned short* __restrict__ z0) {
    __shared__ int h4[4 * BROWS];
    __shared__ int sc[BROWS];
    __shared__ int cur4[4 * BROWS];
    __shared__ float sInv[BROWS];
    int b = blockIdx.x, t = threadIdx.x, w = t >> 6;
    int base = bktBase[b];
    int n = bktBase[b + 1] - base;
    h4[t] = 0; h4[256 + t] = 0; h4[512 + t] = 0; h4[768 + t] = 0;
    __syncthreads();
    int* hw = h4 + w * BROWS;
    for (int i = t; i < n; i += 256)
        atomicAdd(&hw[bins[base + i] >> 18], 1);
    __syncthreads();
    int v = h4[t] + h4[256 + t] + h4[512 + t] + h4[768 + t];
    sc[t] = v;
    __syncthreads();
    for (int o = 1; o < 256; o <<= 1) {
        int x = (t >= o) ? sc[t - o] : 0;
        __syncthreads();
        sc[t] += x;
        __syncthreads();
    }
    int excl = sc[t] - v;
    int row = b * BROWS + t;
    if (row < N) row_ptr[row] = base + excl;
    sInv[t] = (v > 0) ? (1.0f / sqrtf((float)v)) : 0.0f;
    // per-wave cursor bases (wave w places its own subset, no cross-wave atomics)
    cur4[t]       = excl;
    cur4[256 + t] = excl + h4[t];
    cur4[512 + t] = excl + h4[t] + h4[256 + t];
    cur4[768 + t] = excl + h4[t] + h4[256 + t] + h4[512 + t];
    __syncthreads();
    // fused z0 = inv .* x0 (bf16 RTNE), 16 rows per pass, coalesced
    int rf = t & 15, rg = t >> 4;
    for (int pass = 0; pass < 16; pass++) {
        int r = pass * 16 + rg;
        int rr = b * BROWS + r;
        if (rr < N) {
            const float4* src = (rr < nU)
                ? ((const float4*)ue) + (size_t)rr * 16
                : ((const float4*)ie) + (size_t)(rr - nU) * 16;
            float4 val = src[rf];
            float scl = sInv[r];
            ushort4 o;
            o.x = f2bf(val.x * scl);
            o.y = f2bf(val.y * scl);
            o.z = f2bf(val.z * scl);
            o.w = f2bf(val.w * scl);
            ((ushort4*)z0)[(size_t)rr * 16 + rf] = o;
        }
    }
    // placement with per-wave cursors (same i -> thread mapping as histogram)
    int* cw = cur4 + w * BROWS;
    for (int i = t; i < n; i += 256) {
        int p = bins[base + i];
        int pos = base + atomicAdd(&cw[p >> 18], 1);
        col[pos] = p & SRCMASK;
    }
}

// ---------------- SPMM (bf16, 4-deep unroll) + fused batch-accumulate tail -------
__global__ void k_spmm(const int* __restrict__ row_ptr, const int* __restrict__ col,
                       const unsigned short* __restrict__ x,
                       unsigned short* __restrict__ y, int N, int nBlkMain,
                       const int* __restrict__ users, const int* __restrict__ items,
                       int B, int nU,
                       const float* __restrict__ ue, const float* __restrict__ ie,
                       float* __restrict__ acc, int mode) {
    int t = threadIdx.x;
    int grp = t >> 4, f4 = t & 15;
    const ushort4* x4 = (const ushort4*)x;
    if ((int)blockIdx.x < nBlkMain) {
        int row = blockIdx.x * 16 + grp;
        if (row >= N) return;
        int s = row_ptr[row], e = row_ptr[row + 1];
        float4 a0 = make_float4(0.f, 0.f, 0.f, 0.f);
        float4 a1 = make_float4(0.f, 0.f, 0.f, 0.f);
        float4 a2 = make_float4(0.f, 0.f, 0.f, 0.f);
        float4 a3 = make_float4(0.f, 0.f, 0.f, 0.f);
        int j = s;
        for (; j + 3 < e; j += 4) {
            int c0 = col[j], c1 = col[j + 1], c2 = col[j + 2], c3 = col[j + 3];
            ushort4 v0 = x4[(size_t)c0 * 16 + f4];
            ushort4 v1 = x4[(size_t)c1 * 16 + f4];
            ushort4 v2 = x4[(size_t)c2 * 16 + f4];
            ushort4 v3 = x4[(size_t)c3 * 16 + f4];
            a0.x += bf2f(v0.x); a0.y += bf2f(v0.y); a0.z += bf2f(v0.z); a0.w += bf2f(v0.w);
            a1.x += bf2f(v1.x); a1.y += bf2f(v1.y); a1.z += bf2f(v1.z); a1.w += bf2f(v1.w);
            a2.x += bf2f(v2.x); a2.y += bf2f(v2.y); a2.z += bf2f(v2.z); a2.w += bf2f(v2.w);
            a3.x += bf2f(v3.x); a3.y += bf2f(v3.y); a3.z += bf2f(v3.z); a3.w += bf2f(v3.w);
        }
        for (; j < e; j++) {
            int c = col[j];
            ushort4 v = x4[(size_t)c * 16 + f4];
            a0.x += bf2f(v.x); a0.y += bf2f(v.y); a0.z += bf2f(v.z); a0.w += bf2f(v.w);
        }
        float rdeg = (e > s) ? (1.0f / (float)(e - s)) : 0.0f;
        ushort4 o;
        o.x = f2bf((a0.x + a1.x + a2.x + a3.x) * rdeg);
        o.y = f2bf((a0.y + a1.y + a2.y + a3.y) * rdeg);
        o.z = f2bf((a0.z + a1.z + a2.z + a3.z) * rdeg);
        o.w = f2bf((a0.w + a1.w + a2.w + a3.w) * rdeg);
        ((ushort4*)y)[(size_t)row * 16 + f4] = o;
    } else {
        int b = (blockIdx.x - nBlkMain) * 16 + grp;
        if (b >= 2 * B) return;
        float4 c;
        if (mode == 0) {
            const float4* x0 = (b < B)
                ? ((const float4*)ue) + (size_t)users[b] * 16
                : ((const float4*)ie) + (size_t)items[b - B] * 16;
            c = x0[f4];
        } else {
            int row = (b < B) ? users[b] : (nU + items[b - B]);
            int deg = row_ptr[row + 1] - row_ptr[row];
            float f = sqrtf((float)deg);
            ushort4 v = x4[(size_t)row * 16 + f4];
            c = ((const float4*)acc)[(size_t)b * 16 + f4];
            c.x += f * bf2f(v.x); c.y += f * bf2f(v.y);
            c.z += f * bf2f(v.z); c.w += f * bf2f(v.w);
        }
        ((float4*)acc)[(size_t)b * 16 + f4] = c;
    }
}

// ---------------- layer-3 + layer-4 terms at batch rows only ---------------------
// acc[b] += sqrt(deg)*z3[row] + sqrt(deg)*(1/deg)*sum_{c in N(row)} z3[c]
__global__ void k_tail34(const int* __restrict__ row_ptr, const int* __restrict__ col,
                         const unsigned short* __restrict__ z3,
                         const int* __restrict__ users, const int* __restrict__ items,
                         int B, int nU, float* __restrict__ acc) {
    int t = threadIdx.x, grp = t >> 4, f4 = t & 15;
    int b = blockIdx.x * 16 + grp;
    if (b >= 2 * B) return;
    int row = (b < B) ? users[b] : (nU + items[b - B]);
    int s = row_ptr[row], e = row_ptr[row + 1];
    const ushort4* x4 = (const ushort4*)z3;
    float4 c = ((const float4*)acc)[(size_t)b * 16 + f4];
    if (e > s) {
        float f = sqrtf((float)(e - s));
        ushort4 v = x4[(size_t)row * 16 + f4];
        c.x += f * bf2f(v.x); c.y += f * bf2f(v.y);
        c.z += f * bf2f(v.z); c.w += f * bf2f(v.w);
        float4 a0 = make_float4(0.f, 0.f, 0.f, 0.f);
        float4 a1 = make_float4(0.f, 0.f, 0.f, 0.f);
        int j = s;
        for (; j + 1 < e; j += 2) {
            ushort4 v0 = x4[(size_t)col[j] * 16 + f4];
            ushort4 v1 = x4[(size_t)col[j + 1] * 16 + f4];
            a0.x += bf2f(v0.x); a0.y += bf2f(v0.y); a0.z += bf2f(v0.z); a0.w += bf2f(v0.w);
            a1.x += bf2f(v1.x); a1.y += bf2f(v1.y); a1.z += bf2f(v1.z); a1.w += bf2f(v1.w);
        }
        if (j < e) {
            ushort4 v0 = x4[(size_t)col[j] * 16 + f4];
            a0.x += bf2f(v0.x); a0.y += bf2f(v0.y); a0.z += bf2f(v0.z); a0.w += bf2f(v0.w);
        }
        float scale = f / (float)(e - s);
        c.x += scale * (a0.x + a1.x); c.y += scale * (a0.y + a1.y);
        c.z += scale * (a0.z + a1.z); c.w += scale * (a0.w + a1.w);
    }
    ((float4*)acc)[(size_t)b * 16 + f4] = c;
}

// ---------------- final: gamma[b] = dot(acc_u[b], acc_i[b]) / 25 -----------------
__global__ void k_dot(const float* __restrict__ acc, int B, float* __restrict__ out) {
    int b = blockIdx.x * (blockDim.x >> 6) + (threadIdx.x >> 6);
    int lane = threadIdx.x & 63;
    if (b >= B) return;
    float p = acc[(size_t)b * 64 + lane] * acc[(size_t)(b + B) * 64 + lane];
    #pragma unroll
    for (int o = 32; o > 0; o >>= 1) p += __shfl_down(p, o, WAVE);
    if (lane == 0) out[b] = p * (1.0f / 25.0f);
}

extern "C" void kernel_launch(void* const* d_in, const int* in_sizes, int n_in,
                              void* d_out, int out_size, void* d_ws, size_t ws_size,
                              hipStream_t stream) {
    const int*   users = (const int*)d_in[0];
    const int*   items = (const int*)d_in[1];
    const int*   eu    = (const int*)d_in[2];
    const int*   ei    = (const int*)d_in[3];
    const float* ue    = (const float*)d_in[4];
    const float* ie    = (const float*)d_in[5];
    float* out = (float*)d_out;

    const int D  = 64;
    const int B  = in_sizes[0];
    const int nE = in_sizes[2];
    const int nU = in_sizes[4] / D;
    const int nI = in_sizes[5] / D;
    const int N  = nU + nI;
    const int nBkt = (N + BROWS - 1) / BROWS;   // 586 (<= NBKT_MAX required)
    const int total = 2 * nE;

    const int nBlkB = (nE + EPB - 1) / EPB;     // 293 build blocks w/ edges
    const int nJg   = (nBlkB + 7) / 8;          // 38
    const int nJ    = 8 * nJg;                  // 304 (empty blocks write zero rows)

    // ---- carve workspace (256B-aligned chunks) ----
    char* p = (char*)d_ws;
    auto alloc = [&](size_t bytes) -> void* {
        void* r = (void*)p;
        p += (bytes + 255) & ~(size_t)255;
        return r;
    };
    int*   cntBB   = (int*)  alloc((size_t)nJ * nBkt * 4);     // 0.7 MB
    int*   baseBB  = (int*)  alloc((size_t)nBkt * nJ * 4);     // 0.7 MB
    int*   bktTot  = (int*)  alloc((size_t)nBkt * 4);
    int*   bktBase = (int*)  alloc((size_t)(nBkt + 1) * 4);
    int*   bins    = (int*)  alloc((size_t)total * 4);         // 4.8 MB packed
    int*   col     = (int*)  alloc((size_t)total * 4);         // 4.8 MB
    int*   row_ptr = (int*)  alloc((size_t)(N + 1) * 4);
    unsigned short* za = (unsigned short*)alloc((size_t)N * D * 2);  // 19.2 MB bf16
    unsigned short* zb = (unsigned short*)alloc((size_t)N * D * 2);  // 19.2 MB bf16
    float* acc     = (float*)alloc((size_t)2 * B * D * 4);

    // ---- build CSR: zero global atomics ----
    k_hist<<<nJ, 256, 0, stream>>>(eu, ei, nE, nU, nBkt, nJg, cntBB);
    k_scanBkt<<<nBkt, 256, 0, stream>>>(cntBB, baseBB, bktTot, nBkt, nJ);
    k_scanTot<<<1, 1024, 0, stream>>>(bktTot, bktBase, row_ptr, nBkt, N, total);
    k_bin<<<nJ, 256, 0, stream>>>(eu, ei, nE, nU, nBkt, nJ, nJg, baseBB, bktBase, bins);
    k_csrz<<<nBkt, BROWS, 0, stream>>>(bins, bktBase, N, nU, ue, ie, row_ptr, col, za);

    // ---- 3 full propagation layers (z1,z2,z3), batch-accumulate fused in tail ----
    const int nBlkMain = (N + 15) / 16;
    const int nBlkTail = (2 * B + 15) / 16;
    unsigned short* zin = za;
    unsigned short* zout = zb;
    for (int l = 0; l < 3; l++) {
        k_spmm<<<nBlkMain + nBlkTail, 256, 0, stream>>>(
            row_ptr, col, zin, zout, N, nBlkMain,
            users, items, B, nU, ue, ie, acc, (l == 0) ? 0 : 1);
        unsigned short* t = zin; zin = zout; zout = t;
    }

    // ---- layer-3 + layer-4 terms at batch rows only, then dot ----
    k_tail34<<<nBlkTail, 256, 0, stream>>>(row_ptr, col, zin, users, items, B, nU, acc);
    k_dot<<<(B + 3) / 4, 256, 0, stream>>>(acc, B, out);
}

// Round 13
// 220.201 us; speedup vs baseline: 1.9950x; 1.2155x over previous
//
#include <hip/hip_runtime.h>

#define WAVE 64
#define BROWS 256        // rows per bucket (bucket = node >> 8)
#define NBKT_MAX 1024
#define CMAX 4           // max per-thread chunk in k_scanBkt (nJ <= 256*CMAX)
#define SRCMASK 0x3FFFF  // 18-bit src field in packed bins entry
#define EPB 2048         // edges per build block (256 threads x 8)
#define ENTCAP 4096      // LDS entry cache per bucket in k_csrz

// z stored BF16 row-major z[node][64] (128 B). Accumulation fp32 throughout.

__device__ __forceinline__ unsigned short f2bf(float f) {
    unsigned u = __float_as_uint(f);
    u += 0x7FFF + ((u >> 16) & 1);   // round-to-nearest-even
    return (unsigned short)(u >> 16);
}
__device__ __forceinline__ float bf2f(unsigned short v) {
    return __uint_as_float((unsigned)v << 16);
}
// unpack uint4 (8 bf16) and add into a[8]
__device__ __forceinline__ void addbf8(float* a, uint4 v) {
    a[0] += __uint_as_float(v.x << 16);
    a[1] += __uint_as_float(v.x & 0xFFFF0000u);
    a[2] += __uint_as_float(v.y << 16);
    a[3] += __uint_as_float(v.y & 0xFFFF0000u);
    a[4] += __uint_as_float(v.z << 16);
    a[5] += __uint_as_float(v.z & 0xFFFF0000u);
    a[6] += __uint_as_float(v.w << 16);
    a[7] += __uint_as_float(v.w & 0xFFFF0000u);
}

// ---------------- phase 1: per-block bucket histogram (2048 edges/block) --------
__global__ void k_hist(const int* __restrict__ eu, const int* __restrict__ ei,
                       int nE, int nU, int nBkt, int nJg, int* __restrict__ cntBB) {
    __shared__ int h4[4 * NBKT_MAX];
    for (int i = threadIdx.x; i < 4 * nBkt; i += 256) h4[i] = 0;
    __syncthreads();
    int* hw = h4 + (threadIdx.x >> 6) * nBkt;    // per-wave sub-histogram
    const int4* eu4 = (const int4*)eu;
    const int4* ei4 = (const int4*)ei;
    for (int pass = 0; pass < 2; pass++) {
        int i4 = blockIdx.x * 512 + pass * 256 + threadIdx.x;
        int e0 = i4 * 4;
        if (e0 + 3 < nE) {
            int4 u = eu4[i4];
            int4 v = ei4[i4];
            atomicAdd(&hw[u.x >> 8], 1); atomicAdd(&hw[(nU + v.x) >> 8], 1);
            atomicAdd(&hw[u.y >> 8], 1); atomicAdd(&hw[(nU + v.y) >> 8], 1);
            atomicAdd(&hw[u.z >> 8], 1); atomicAdd(&hw[(nU + v.z) >> 8], 1);
            atomicAdd(&hw[u.w >> 8], 1); atomicAdd(&hw[(nU + v.w) >> 8], 1);
        } else if (e0 < nE) {
            for (int e = e0; e < nE; e++) {
                atomicAdd(&hw[eu[e] >> 8], 1);
                atomicAdd(&hw[(nU + ei[e]) >> 8], 1);
            }
        }
    }
    __syncthreads();
    int j = (blockIdx.x & 7) * nJg + (blockIdx.x >> 3);   // XCD-affine block order
    int* dst = cntBB + (size_t)j * nBkt;
    for (int i = threadIdx.x; i < nBkt; i += 256)
        dst[i] = h4[i] + h4[nBkt + i] + h4[2 * nBkt + i] + h4[3 * nBkt + i];
}

// ---------------- phase 2a: per-bucket scan over blocks -> fragment bases --------
__global__ void k_scanBkt(const int* __restrict__ cntBB, int* __restrict__ baseBB,
                          int* __restrict__ bktTot, int nBkt, int nJ) {
    __shared__ int s[256];
    int b = blockIdx.x, t = threadIdx.x;
    int C = (nJ + 255) / 256;
    int vals[CMAX];
    int sum = 0;
    for (int k = 0; k < CMAX; k++) {
        if (k >= C) break;
        int j = t * C + k;
        int v = (j < nJ) ? cntBB[(size_t)j * nBkt + b] : 0;
        vals[k] = v; sum += v;
    }
    s[t] = sum;
    __syncthreads();
    for (int o = 1; o < 256; o <<= 1) {
        int x = (t >= o) ? s[t - o] : 0;
        __syncthreads();
        s[t] += x;
        __syncthreads();
    }
    int run = s[t] - sum;  // exclusive
    for (int k = 0; k < CMAX; k++) {
        if (k >= C) break;
        int j = t * C + k;
        if (j < nJ) { baseBB[(size_t)b * nJ + j] = run; run += vals[k]; }
    }
    if (t == 0) bktTot[b] = s[255];
}

// ---------------- phase 2b: scan bucket totals -> bktBase, row_ptr[N] ------------
__global__ void k_scanTot(const int* __restrict__ bktTot, int* __restrict__ bktBase,
                          int* __restrict__ row_ptr, int nBkt, int N, int total) {
    __shared__ int s[1024];
    int t = threadIdx.x;
    int v = (t < nBkt) ? bktTot[t] : 0;
    s[t] = v;
    __syncthreads();
    for (int o = 1; o < 1024; o <<= 1) {
        int x = (t >= o) ? s[t - o] : 0;
        __syncthreads();
        s[t] += x;
        __syncthreads();
    }
    if (t < nBkt) bktBase[t] = s[t] - v;
    if (t == 0) { bktBase[nBkt] = total; row_ptr[N] = total; }
}

// ---------------- phase 3: bin packed entries (2048 edges/block) -----------------
// entry = ((dst & 255) << 18) | src.  Plain stores: frontier lines are
// block-private and fill in (same-XCD) L2 — NT would force 4B HBM RMW.
__global__ void k_bin(const int* __restrict__ eu, const int* __restrict__ ei,
                      int nE, int nU, int nBkt, int nJ, int nJg,
                      const int* __restrict__ baseBB, const int* __restrict__ bktBase,
                      int* __restrict__ bins) {
    __shared__ int cur[NBKT_MAX];
    int j = (blockIdx.x & 7) * nJg + (blockIdx.x >> 3);
    for (int i = threadIdx.x; i < nBkt; i += 256)
        cur[i] = bktBase[i] + baseBB[(size_t)i * nJ + j];
    __syncthreads();
    const int4* eu4 = (const int4*)eu;
    const int4* ei4 = (const int4*)ei;
    for (int pass = 0; pass < 2; pass++) {
        int i4 = blockIdx.x * 512 + pass * 256 + threadIdx.x;
        int e0 = i4 * 4;
        if (e0 + 3 < nE) {
            int4 uu = eu4[i4];
            int4 vv = ei4[i4];
            #pragma unroll
            for (int k = 0; k < 4; k++) {
                int u = (k == 0) ? uu.x : (k == 1) ? uu.y : (k == 2) ? uu.z : uu.w;
                int i2 = (k == 0) ? vv.x : (k == 1) ? vv.y : (k == 2) ? vv.z : vv.w;
                int v = nU + i2;
                int p1 = atomicAdd(&cur[u >> 8], 1);
                int p2 = atomicAdd(&cur[v >> 8], 1);
                bins[p1] = ((u & 255) << 18) | v;
                bins[p2] = ((v & 255) << 18) | u;
            }
        } else if (e0 < nE) {
            for (int e = e0; e < nE; e++) {
                int u = eu[e];
                int v = nU + ei[e];
                int p1 = atomicAdd(&cur[u >> 8], 1);
                int p2 = atomicAdd(&cur[v >> 8], 1);
                bins[p1] = ((u & 255) << 18) | v;
                bins[p2] = ((v & 255) << 18) | u;
            }
        }
    }
}

// ---------------- phase 4: CSR finalize, LDS entry cache, fused z0 ---------------
__global__ void k_csrz(const int* __restrict__ bins, const int* __restrict__ bktBase,
                       int N, int nU,
                       const float* __restrict__ ue, const float* __restrict__ ie,
                       int* __restrict__ row_ptr, int* __restrict__ col,
                       unsigned short* __restrict__ z0) {
    __shared__ int ent[ENTCAP];
    __shared__ int h4[4 * BROWS];
    __shared__ int sc[BROWS];
    __shared__ int cur4[4 * BROWS];
    __shared__ float sInv[BROWS];
    int b = blockIdx.x, t = threadIdx.x, w = t >> 6;
    int base = bktBase[b];
    int n = bktBase[b + 1] - base;
    h4[t] = 0; h4[256 + t] = 0; h4[512 + t] = 0; h4[768 + t] = 0;
    __syncthreads();
    int* hw = h4 + w * BROWS;
    for (int i = t; i < n; i += 256) {
        int p = bins[base + i];
        if (i < ENTCAP) ent[i] = p;
        atomicAdd(&hw[p >> 18], 1);
    }
    __syncthreads();
    int v = h4[t] + h4[256 + t] + h4[512 + t] + h4[768 + t];
    sc[t] = v;
    __syncthreads();
    for (int o = 1; o < 256; o <<= 1) {
        int x = (t >= o) ? sc[t - o] : 0;
        __syncthreads();
        sc[t] += x;
        __syncthreads();
    }
    int excl = sc[t] - v;
    int row = b * BROWS + t;
    if (row < N) row_ptr[row] = base + excl;
    sInv[t] = (v > 0) ? (1.0f / sqrtf((float)v)) : 0.0f;
    // per-wave cursor bases (wave w places its own subset, no cross-wave atomics)
    cur4[t]       = excl;
    cur4[256 + t] = excl + h4[t];
    cur4[512 + t] = excl + h4[t] + h4[256 + t];
    cur4[768 + t] = excl + h4[t] + h4[256 + t] + h4[512 + t];
    __syncthreads();
    // fused z0 = inv .* x0 (bf16 RTNE), 16 rows per pass, coalesced
    int rf = t & 15, rg = t >> 4;
    for (int pass = 0; pass < 16; pass++) {
        int r = pass * 16 + rg;
        int rr = b * BROWS + r;
        if (rr < N) {
            const float4* src = (rr < nU)
                ? ((const float4*)ue) + (size_t)rr * 16
                : ((const float4*)ie) + (size_t)(rr - nU) * 16;
            float4 val = src[rf];
            float scl = sInv[r];
            ushort4 o;
            o.x = f2bf(val.x * scl);
            o.y = f2bf(val.y * scl);
            o.z = f2bf(val.z * scl);
            o.w = f2bf(val.w * scl);
            ((ushort4*)z0)[(size_t)rr * 16 + rf] = o;
        }
    }
    // placement with per-wave cursors (same i -> thread mapping as histogram)
    int* cw = cur4 + w * BROWS;
    for (int i = t; i < n; i += 256) {
        int p = (i < ENTCAP) ? ent[i] : bins[base + i];
        int pos = base + atomicAdd(&cw[p >> 18], 1);
        col[pos] = p & SRCMASK;
    }
}

// ---------------- SPMM (bf16, 8-lane x 16B groups) + fused batch tail ------------
__global__ void k_spmm(const int* __restrict__ row_ptr, const int* __restrict__ col,
                       const unsigned short* __restrict__ x,
                       unsigned short* __restrict__ y, int N, int nBlkMain,
                       const int* __restrict__ users, const int* __restrict__ items,
                       int B, int nU,
                       const float* __restrict__ ue, const float* __restrict__ ie,
                       float* __restrict__ acc, int mode) {
    int t = threadIdx.x;
    if ((int)blockIdx.x < nBlkMain) {
        int grp = t >> 3, f = t & 7;          // 32 rows/block, 16B/lane
        int row = blockIdx.x * 32 + grp;
        if (row >= N) return;
        const uint4* x8 = (const uint4*)x;    // row stride = 8 uint4
        int s = row_ptr[row], e = row_ptr[row + 1];
        float a0[8] = {0,0,0,0,0,0,0,0};
        float a1[8] = {0,0,0,0,0,0,0,0};
        float a2[8] = {0,0,0,0,0,0,0,0};
        float a3[8] = {0,0,0,0,0,0,0,0};
        int j = s;
        for (; j + 3 < e; j += 4) {
            int c0 = col[j], c1 = col[j + 1], c2 = col[j + 2], c3 = col[j + 3];
            uint4 v0 = x8[(size_t)c0 * 8 + f];
            uint4 v1 = x8[(size_t)c1 * 8 + f];
            uint4 v2 = x8[(size_t)c2 * 8 + f];
            uint4 v3 = x8[(size_t)c3 * 8 + f];
            addbf8(a0, v0); addbf8(a1, v1); addbf8(a2, v2); addbf8(a3, v3);
        }
        for (; j < e; j++) {
            uint4 v = x8[(size_t)col[j] * 8 + f];
            addbf8(a0, v);
        }
        float rdeg = (e > s) ? (1.0f / (float)(e - s)) : 0.0f;
        uint4 o;
        float s0, s1;
        s0 = (a0[0]+a1[0]+a2[0]+a3[0]) * rdeg; s1 = (a0[1]+a1[1]+a2[1]+a3[1]) * rdeg;
        o.x = (unsigned)f2bf(s0) | ((unsigned)f2bf(s1) << 16);
        s0 = (a0[2]+a1[2]+a2[2]+a3[2]) * rdeg; s1 = (a0[3]+a1[3]+a2[3]+a3[3]) * rdeg;
        o.y = (unsigned)f2bf(s0) | ((unsigned)f2bf(s1) << 16);
        s0 = (a0[4]+a1[4]+a2[4]+a3[4]) * rdeg; s1 = (a0[5]+a1[5]+a2[5]+a3[5]) * rdeg;
        o.z = (unsigned)f2bf(s0) | ((unsigned)f2bf(s1) << 16);
        s0 = (a0[6]+a1[6]+a2[6]+a3[6]) * rdeg; s1 = (a0[7]+a1[7]+a2[7]+a3[7]) * rdeg;
        o.w = (unsigned)f2bf(s0) | ((unsigned)f2bf(s1) << 16);
        ((uint4*)y)[(size_t)row * 8 + f] = o;
    } else {
        int grp = t >> 4, f4 = t & 15;
        int b = (blockIdx.x - nBlkMain) * 16 + grp;
        if (b >= 2 * B) return;
        const ushort4* x4 = (const ushort4*)x;
        float4 c;
        if (mode == 0) {
            const float4* x0 = (b < B)
                ? ((const float4*)ue) + (size_t)users[b] * 16
                : ((const float4*)ie) + (size_t)items[b - B] * 16;
            c = x0[f4];
        } else {
            int row = (b < B) ? users[b] : (nU + items[b - B]);
            int deg = row_ptr[row + 1] - row_ptr[row];
            float f = sqrtf((float)deg);
            ushort4 v = x4[(size_t)row * 16 + f4];
            c = ((const float4*)acc)[(size_t)b * 16 + f4];
            c.x += f * bf2f(v.x); c.y += f * bf2f(v.y);
            c.z += f * bf2f(v.z); c.w += f * bf2f(v.w);
        }
        ((float4*)acc)[(size_t)b * 16 + f4] = c;
    }
}

// ---------------- layer-3 + layer-4 terms at batch rows only ---------------------
// acc[b] += sqrt(deg)*z3[row] + sqrt(deg)/deg * sum_{c in N(row)} z3[c]
__global__ void k_tail34(const int* __restrict__ row_ptr, const int* __restrict__ col,
                         const unsigned short* __restrict__ z3,
                         const int* __restrict__ users, const int* __restrict__ items,
                         int B, int nU, float* __restrict__ acc) {
    int t = threadIdx.x, grp = t >> 3, f = t & 7;
    int b = blockIdx.x * 32 + grp;
    if (b >= 2 * B) return;
    int row = (b < B) ? users[b] : (nU + items[b - B]);
    int s = row_ptr[row], e = row_ptr[row + 1];
    const uint4* x8 = (const uint4*)z3;
    float4 cA = ((const float4*)acc)[(size_t)b * 16 + 2 * f];
    float4 cB = ((const float4*)acc)[(size_t)b * 16 + 2 * f + 1];
    if (e > s) {
        float fq = sqrtf((float)(e - s));
        float a0[8] = {0,0,0,0,0,0,0,0};
        float a1[8] = {0,0,0,0,0,0,0,0};
        int j = s;
        for (; j + 1 < e; j += 2) {
            uint4 v0 = x8[(size_t)col[j] * 8 + f];
            uint4 v1 = x8[(size_t)col[j + 1] * 8 + f];
            addbf8(a0, v0); addbf8(a1, v1);
        }
        if (j < e) {
            uint4 v0 = x8[(size_t)col[j] * 8 + f];
            addbf8(a0, v0);
        }
        uint4 vs = x8[(size_t)row * 8 + f];
        float self[8] = {0,0,0,0,0,0,0,0};
        addbf8(self, vs);
        float scale = fq / (float)(e - s);
        cA.x += fq * self[0] + scale * (a0[0] + a1[0]);
        cA.y += fq * self[1] + scale * (a0[1] + a1[1]);
        cA.z += fq * self[2] + scale * (a0[2] + a1[2]);
        cA.w += fq * self[3] + scale * (a0[3] + a1[3]);
        cB.x += fq * self[4] + scale * (a0[4] + a1[4]);
        cB.y += fq * self[5] + scale * (a0[5] + a1[5]);
        cB.z += fq * self[6] + scale * (a0[6] + a1[6]);
        cB.w += fq * self[7] + scale * (a0[7] + a1[7]);
    }
    ((float4*)acc)[(size_t)b * 16 + 2 * f]     = cA;
    ((float4*)acc)[(size_t)b * 16 + 2 * f + 1] = cB;
}

// ---------------- final: gamma[b] = dot(acc_u[b], acc_i[b]) / 25 -----------------
__global__ void k_dot(const float* __restrict__ acc, int B, float* __restrict__ out) {
    int b = blockIdx.x * (blockDim.x >> 6) + (threadIdx.x >> 6);
    int lane = threadIdx.x & 63;
    if (b >= B) return;
    float p = acc[(size_t)b * 64 + lane] * acc[(size_t)(b + B) * 64 + lane];
    #pragma unroll
    for (int o = 32; o > 0; o >>= 1) p += __shfl_down(p, o, WAVE);
    if (lane == 0) out[b] = p * (1.0f / 25.0f);
}

extern "C" void kernel_launch(void* const* d_in, const int* in_sizes, int n_in,
                              void* d_out, int out_size, void* d_ws, size_t ws_size,
                              hipStream_t stream) {
    const int*   users = (const int*)d_in[0];
    const int*   items = (const int*)d_in[1];
    const int*   eu    = (const int*)d_in[2];
    const int*   ei    = (const int*)d_in[3];
    const float* ue    = (const float*)d_in[4];
    const float* ie    = (const float*)d_in[5];
    float* out = (float*)d_out;

    const int D  = 64;
    const int B  = in_sizes[0];
    const int nE = in_sizes[2];
    const int nU = in_sizes[4] / D;
    const int nI = in_sizes[5] / D;
    const int N  = nU + nI;
    const int nBkt = (N + BROWS - 1) / BROWS;   // 586 (<= NBKT_MAX required)
    const int total = 2 * nE;

    const int nBlkB = (nE + EPB - 1) / EPB;     // 293 build blocks w/ edges
    const int nJg   = (nBlkB + 7) / 8;          // 38
    const int nJ    = 8 * nJg;                  // 304 (empty blocks write zero rows)

    // ---- carve workspace (256B-aligned chunks) ----
    char* p = (char*)d_ws;
    auto alloc = [&](size_t bytes) -> void* {
        void* r = (void*)p;
        p += (bytes + 255) & ~(size_t)255;
        return r;
    };
    int*   cntBB   = (int*)  alloc((size_t)nJ * nBkt * 4);     // 0.7 MB
    int*   baseBB  = (int*)  alloc((size_t)nBkt * nJ * 4);     // 0.7 MB
    int*   bktTot  = (int*)  alloc((size_t)nBkt * 4);
    int*   bktBase = (int*)  alloc((size_t)(nBkt + 1) * 4);
    int*   bins    = (int*)  alloc((size_t)total * 4);         // 4.8 MB packed
    int*   col     = (int*)  alloc((size_t)total * 4);         // 4.8 MB
    int*   row_ptr = (int*)  alloc((size_t)(N + 1) * 4);
    unsigned short* za = (unsigned short*)alloc((size_t)N * D * 2);  // 19.2 MB bf16
    unsigned short* zb = (unsigned short*)alloc((size_t)N * D * 2);  // 19.2 MB bf16
    float* acc     = (float*)alloc((size_t)2 * B * D * 4);

    // ---- build CSR: zero global atomics ----
    k_hist<<<nJ, 256, 0, stream>>>(eu, ei, nE, nU, nBkt, nJg, cntBB);
    k_scanBkt<<<nBkt, 256, 0, stream>>>(cntBB, baseBB, bktTot, nBkt, nJ);
    k_scanTot<<<1, 1024, 0, stream>>>(bktTot, bktBase, row_ptr, nBkt, N, total);
    k_bin<<<nJ, 256, 0, stream>>>(eu, ei, nE, nU, nBkt, nJ, nJg, baseBB, bktBase, bins);
    k_csrz<<<nBkt, BROWS, 0, stream>>>(bins, bktBase, N, nU, ue, ie, row_ptr, col, za);

    // ---- 3 full propagation layers (z1,z2,z3), batch-accumulate fused in tail ----
    const int nBlkMain = (N + 31) / 32;
    const int nBlkTail = (2 * B + 15) / 16;
    unsigned short* zin = za;
    unsigned short* zout = zb;
    for (int l = 0; l < 3; l++) {
        k_spmm<<<nBlkMain + nBlkTail, 256, 0, stream>>>(
            row_ptr, col, zin, zout, N, nBlkMain,
            users, items, B, nU, ue, ie, acc, (l == 0) ? 0 : 1);
        unsigned short* t = zin; zin = zout; zout = t;
    }

    // ---- layer-3 + layer-4 terms at batch rows only, then dot ----
    const int nBlkT34 = (2 * B + 31) / 32;
    k_tail34<<<nBlkT34, 256, 0, stream>>>(row_ptr, col, zin, users, items, B, nU, acc);
    k_dot<<<(B + 3) / 4, 256, 0, stream>>>(acc, B, out);
}